// Round 10
// baseline (246.237 us; speedup 1.0000x reference)
//
#include <hip/hip_runtime.h>
#include <hip/hip_bf16.h>

// ---- problem dims (compile-time) ----
#define DIM     1024
#define DINNER  2048
#define NSTATE  16
#define DTRANK  64
#define DCONV   4
#define BATCH   2
#define SEQ     1024
#define BL      (BATCH*SEQ)     // 2048 rows
#define XDBLW   96              // DTRANK + 2*NSTATE
#define NCHUNK  32
#define TCHUNK  32              // SEQ / NCHUNK
#define KSLICE  16              // split-K factor for G2

typedef __attribute__((ext_vector_type(4))) float  f32x4;
typedef __attribute__((ext_vector_type(8))) short  bf16x8;
typedef unsigned short ushort_t;

__device__ __forceinline__ ushort_t f2bf(float f) {
    union { float f; unsigned int u; } v; v.f = f;
    unsigned int lsb = (v.u >> 16) & 1u;
    v.u += 0x7fffu + lsb;
    return (ushort_t)(v.u >> 16);
}
__device__ __forceinline__ float bf2f(ushort_t h) {
    union { unsigned u; float f; } v; v.u = ((unsigned)h) << 16; return v.f;
}

typedef __attribute__((address_space(1))) unsigned int gu32_t;
typedef __attribute__((address_space(3))) unsigned int lu32_t;
__device__ __forceinline__ void gload_lds16(const ushort_t* g, ushort_t* l) {
    __builtin_amdgcn_global_load_lds((const gu32_t*)(const void*)g,
                                     (lu32_t*)(void*)l, 16, 0, 0);
}

// ---------------- convert f32 -> bf16 (flat) ----------------
__global__ __launch_bounds__(256) void cvt_f32_bf16(
    const float* __restrict__ src, ushort_t* __restrict__ dst, int n)
{
    int i = (blockIdx.x * 256 + threadIdx.x) * 4;
    if (i >= n) return;
    f32x4 v = *(const f32x4*)(src + i);
    ushort_t r0 = f2bf(v[0]), r1 = f2bf(v[1]), r2 = f2bf(v[2]), r3 = f2bf(v[3]);
    *(uint2*)(dst + i) = make_uint2((unsigned)r0 | ((unsigned)r1 << 16),
                                    (unsigned)r2 | ((unsigned)r3 << 16));
}

// ---------------- transpose f32 (R x C) -> bf16 (C x R), 32x32 tiles ----------------
__global__ __launch_bounds__(256) void transpose_f32_bf16(
    const float* __restrict__ src, ushort_t* __restrict__ dst, int R, int C)
{
    __shared__ float tile[32][33];
    const int tx = threadIdx.x;
    const int ty = threadIdx.y;
    const int r0 = blockIdx.y * 32;
    const int c0 = blockIdx.x * 32;
    #pragma unroll
    for (int i = 0; i < 4; ++i) {
        int r = r0 + ty + i * 8;
        tile[ty + i * 8][tx] = src[(size_t)r * C + c0 + tx];
    }
    __syncthreads();
    #pragma unroll
    for (int i = 0; i < 4; ++i) {
        int c = c0 + ty + i * 8;
        dst[(size_t)c * R + r0 + tx] = f2bf(tile[tx][ty + i * 8]);
    }
}

// ======== m97-style MFMA GEMM: C = A(MxK) * Bt(NxK)^T, full 128-tiles ========
// Output: f32 (Cf) and/or bf16 (Cb).
__global__ __launch_bounds__(256) void gemm_lds(
    const ushort_t* __restrict__ A,  int lda,
    const ushort_t* __restrict__ Bt, int ldb,
    int K,
    float* __restrict__ Cf, ushort_t* __restrict__ Cb, int ldc)
{
    __shared__ ushort_t As[128 * 32];
    __shared__ ushort_t Bs[128 * 32];

    const int tid  = threadIdx.x;
    const int m0   = blockIdx.y * 128;
    const int n0   = blockIdx.x * 128;
    const int wid  = tid >> 6;
    const int lane = tid & 63;
    const int wm   = (wid >> 1) * 64;
    const int wn   = (wid & 1) * 64;
    const int lr   = lane & 15;
    const int lk   = (lane >> 4) * 8;

    const int c0 = wid * 64 + lane;
    const int c1 = 256 + c0;
    const int r0 = c0 >> 2, f0 = (c0 & 3) * 8;
    const int r1 = c1 >> 2, f1 = (c1 & 3) * 8;
    ushort_t* lA0 = &As[(wid * 64) * 8];
    ushort_t* lA1 = &As[(256 + wid * 64) * 8];
    ushort_t* lB0 = &Bs[(wid * 64) * 8];
    ushort_t* lB1 = &Bs[(256 + wid * 64) * 8];

    f32x4 acc[4][4];
    #pragma unroll
    for (int m = 0; m < 4; ++m)
        #pragma unroll
        for (int n = 0; n < 4; ++n)
            acc[m][n] = (f32x4){0.f, 0.f, 0.f, 0.f};

    for (int k0 = 0; k0 < K; k0 += 32) {
        gload_lds16(A  + (size_t)(m0 + r0) * lda + k0 + f0, lA0);
        gload_lds16(A  + (size_t)(m0 + r1) * lda + k0 + f1, lA1);
        gload_lds16(Bt + (size_t)(n0 + r0) * ldb + k0 + f0, lB0);
        gload_lds16(Bt + (size_t)(n0 + r1) * ldb + k0 + f1, lB1);
        __syncthreads();

        bf16x8 af[4], bfr[4];
        #pragma unroll
        for (int m = 0; m < 4; ++m)
            af[m] = *(const bf16x8*)(&As[(wm + m * 16 + lr) * 32 + lk]);
        #pragma unroll
        for (int n = 0; n < 4; ++n)
            bfr[n] = *(const bf16x8*)(&Bs[(wn + n * 16 + lr) * 32 + lk]);

        #pragma unroll
        for (int m = 0; m < 4; ++m)
            #pragma unroll
            for (int n = 0; n < 4; ++n)
                acc[m][n] = __builtin_amdgcn_mfma_f32_16x16x32_bf16(af[m], bfr[n], acc[m][n], 0, 0, 0);
        __syncthreads();
    }

    const int rbase = (lane >> 4) * 4;
    #pragma unroll
    for (int m = 0; m < 4; ++m) {
        #pragma unroll
        for (int n = 0; n < 4; ++n) {
            int col = n0 + wn + n * 16 + lr;
            #pragma unroll
            for (int r = 0; r < 4; ++r) {
                int row = m0 + wm + m * 16 + rbase + r;
                float v = acc[m][n][r];
                if (Cf) Cf[(size_t)row * ldc + col] = v;
                if (Cb) Cb[(size_t)row * ldc + col] = f2bf(v);
            }
        }
    }
}

// ======== G2 split-K: Ppart[ks] = A(128-row tile) * Bt(96xK slice)^T ========
__global__ __launch_bounds__(256) void gemm_n96_splitk(
    const ushort_t* __restrict__ A,    // BL x 2048 (hb)
    const ushort_t* __restrict__ Bt,   // 96 x 2048 (WtXp)
    float* __restrict__ Ppart)         // [KSLICE][BL][96]
{
    __shared__ ushort_t As[128 * 40];
    __shared__ ushort_t Bs[96 * 40];

    const int tid   = threadIdx.x;
    const int ks    = blockIdx.x;
    const int m0    = blockIdx.y * 128;
    const int kbase = ks * (DINNER / KSLICE);
    const int wid   = tid >> 6;
    const int lane  = tid & 63;
    const int wm    = wid * 32;
    const int lr    = lane & 15;
    const int lk    = (lane >> 4) * 8;

    f32x4 acc[2][6];
    #pragma unroll
    for (int m = 0; m < 2; ++m)
        #pragma unroll
        for (int n = 0; n < 6; ++n)
            acc[m][n] = (f32x4){0.f, 0.f, 0.f, 0.f};

    for (int k0 = kbase; k0 < kbase + DINNER / KSLICE; k0 += 32) {
        #pragma unroll
        for (int c = 0; c < 2; ++c) {
            int cid = tid + c * 256;
            int row = cid >> 2, ck = (cid & 3) * 8;
            *(uint4*)(&As[row * 40 + ck]) =
                *(const uint4*)(A + (size_t)(m0 + row) * DINNER + k0 + ck);
        }
        {
            int row = tid >> 2, ck = (tid & 3) * 8;
            *(uint4*)(&Bs[row * 40 + ck]) =
                *(const uint4*)(Bt + (size_t)row * DINNER + k0 + ck);
            if (tid < 128) {
                int cid = 256 + tid;
                int row2 = cid >> 2, ck2 = (cid & 3) * 8;
                *(uint4*)(&Bs[row2 * 40 + ck2]) =
                    *(const uint4*)(Bt + (size_t)row2 * DINNER + k0 + ck2);
            }
        }
        __syncthreads();

        bf16x8 af[2], bfr[6];
        #pragma unroll
        for (int m = 0; m < 2; ++m)
            af[m] = *(const bf16x8*)(&As[(wm + m * 16 + lr) * 40 + lk]);
        #pragma unroll
        for (int n = 0; n < 6; ++n)
            bfr[n] = *(const bf16x8*)(&Bs[(n * 16 + lr) * 40 + lk]);

        #pragma unroll
        for (int m = 0; m < 2; ++m)
            #pragma unroll
            for (int n = 0; n < 6; ++n)
                acc[m][n] = __builtin_amdgcn_mfma_f32_16x16x32_bf16(af[m], bfr[n], acc[m][n], 0, 0, 0);
        __syncthreads();
    }

    const int rbase = (lane >> 4) * 4;
    #pragma unroll
    for (int m = 0; m < 2; ++m) {
        #pragma unroll
        for (int n = 0; n < 6; ++n) {
            int col = n * 16 + lr;
            #pragma unroll
            for (int r = 0; r < 4; ++r) {
                int row = m0 + wm + m * 16 + rbase + r;
                Ppart[((size_t)ks * BL + row) * XDBLW + col] = acc[m][n][r];
            }
        }
    }
}

// reduce split-K partials -> xdbl (f32)
__global__ __launch_bounds__(256) void g2_reduce(
    const float* __restrict__ Ppart, float* __restrict__ xdbl)
{
    int idx = blockIdx.x * 256 + threadIdx.x;
    int row = idx / 24, cg = (idx % 24) * 4;
    f32x4 s = (f32x4){0.f, 0.f, 0.f, 0.f};
    #pragma unroll
    for (int ks = 0; ks < KSLICE; ++ks)
        s += *(const f32x4*)(Ppart + ((size_t)ks * BL + row) * XDBLW + cg);
    *(f32x4*)(xdbl + (size_t)row * XDBLW + cg) = s;
}

// ======== delta = softplus(dlt @ Wdt + dtb) -> bf16 (R6 structure) ========
__global__ __launch_bounds__(256) void delta_kernel(
    const float* __restrict__ xdbl,   // BL x 96, dlt = cols [0,64)
    const float* __restrict__ Wdt,    // 64 x 2048 f32
    const float* __restrict__ dtb,    // 2048
    ushort_t* __restrict__ delta_bf)  // BL x 2048 bf16
{
    __shared__ float dltS[4][DTRANK];  // 1 KB
    const int tid = threadIdx.x;
    const int r0  = blockIdx.x * 4;

    if (tid < 64) {
        int r = tid >> 4, off = (tid & 15) * 4;
        *(f32x4*)&dltS[r][off] = *(const f32x4*)(xdbl + (size_t)(r0 + r) * XDBLW + off);
    }
    __syncthreads();

    float acc0[8], acc1[8], acc2[8], acc3[8];
    #pragma unroll
    for (int j = 0; j < 8; ++j) {
        float bj = dtb[tid + j * 256];
        acc0[j] = bj; acc1[j] = bj; acc2[j] = bj; acc3[j] = bj;
    }

    #pragma unroll 4
    for (int kc = 0; kc < 16; ++kc) {
        f32x4 dv0 = *(const f32x4*)&dltS[0][kc * 4];
        f32x4 dv1 = *(const f32x4*)&dltS[1][kc * 4];
        f32x4 dv2 = *(const f32x4*)&dltS[2][kc * 4];
        f32x4 dv3 = *(const f32x4*)&dltS[3][kc * 4];
        #pragma unroll
        for (int kk = 0; kk < 4; ++kk) {
            const float* wrow = Wdt + (size_t)(kc * 4 + kk) * DINNER + tid;
            #pragma unroll
            for (int j = 0; j < 8; ++j) {
                float w = wrow[j * 256];
                acc0[j] = fmaf(dv0[kk], w, acc0[j]);
                acc1[j] = fmaf(dv1[kk], w, acc1[j]);
                acc2[j] = fmaf(dv2[kk], w, acc2[j]);
                acc3[j] = fmaf(dv3[kk], w, acc3[j]);
            }
        }
    }

    #pragma unroll
    for (int j = 0; j < 8; ++j) {
        int d = tid + j * 256;
        float v0 = acc0[j], v1 = acc1[j], v2 = acc2[j], v3 = acc3[j];
        v0 = (v0 > 20.f) ? v0 : log1pf(expf(v0));
        v1 = (v1 > 20.f) ? v1 : log1pf(expf(v1));
        v2 = (v2 > 20.f) ? v2 : log1pf(expf(v2));
        v3 = (v3 > 20.f) ? v3 : log1pf(expf(v3));
        delta_bf[(size_t)(r0 + 0) * DINNER + d] = f2bf(v0);
        delta_bf[(size_t)(r0 + 1) * DINNER + d] = f2bf(v1);
        delta_bf[(size_t)(r0 + 2) * DINNER + d] = f2bf(v2);
        delta_bf[(size_t)(r0 + 3) * DINNER + d] = f2bf(v3);
    }
}

// ---------------- depthwise causal conv(4) + bias + SiLU (bf16 in/out) ----------------
__global__ __launch_bounds__(256) void conv_silu(
    const ushort_t* __restrict__ xrb,   // BL x 4096 bf16 (xp = cols [0,2048))
    const float* __restrict__ convw,
    const float* __restrict__ convb,
    ushort_t* __restrict__ hb)          // BL x 2048 bf16
{
    const int d  = blockIdx.x * 256 + threadIdx.x;
    const int bt = blockIdx.y;
    const int t  = bt & (SEQ - 1);

    float acc = convb[d];
    #pragma unroll
    for (int j = 0; j < DCONV; ++j) {
        int tt = t + j - (DCONV - 1);
        if (tt >= 0)
            acc += convw[d * DCONV + j] * bf2f(xrb[(size_t)(bt + j - (DCONV - 1)) * 4096 + d]);
    }
    float h = acc / (1.f + expf(-acc));
    hb[(size_t)bt * DINNER + d] = f2bf(h);
}

// ================= chunked parallel selective scan =================
__global__ __launch_bounds__(256) void scan_p1(
    const ushort_t* __restrict__ delta_bf,   // BL x 2048 bf16
    const ushort_t* __restrict__ hb,         // BL x 2048 bf16
    const float* __restrict__ xdbl,          // BL x 96 (B at +64)
    const float* __restrict__ Alog,
    float* __restrict__ Pbuf,
    float* __restrict__ Sbuf)
{
    const int d  = (blockIdx.x & 7) * 256 + threadIdx.x;
    const int bc = blockIdx.x >> 3;
    const int b  = bc >> 5;
    const int c  = bc & (NCHUNK - 1);
    const int t0 = c * TCHUNK;

    float A[NSTATE];
    #pragma unroll
    for (int q = 0; q < 4; ++q) {
        f32x4 al = *(const f32x4*)(Alog + (size_t)d * NSTATE + q * 4);
        #pragma unroll
        for (int j = 0; j < 4; ++j) A[q * 4 + j] = -expf(al[j]);
    }

    float s[NSTATE], pp[NSTATE];
    #pragma unroll
    for (int n = 0; n < NSTATE; ++n) { s[n] = 0.f; pp[n] = 1.f; }

    for (int tt = 0; tt < TCHUNK; ++tt) {
        const size_t row = (size_t)(b * SEQ + t0 + tt);
        float dl = bf2f(delta_bf[row * DINNER + d]);
        float hv = bf2f(hb[row * DINNER + d]);
        float dlh = dl * hv;
        float Bv[NSTATE];
        #pragma unroll
        for (int q = 0; q < 4; ++q) {
            f32x4 bv = *(const f32x4*)(xdbl + row * XDBLW + DTRANK + q * 4);
            #pragma unroll
            for (int j = 0; j < 4; ++j) Bv[q * 4 + j] = bv[j];
        }
        #pragma unroll
        for (int n = 0; n < NSTATE; ++n) {
            float a = expf(dl * A[n]);
            s[n]  = fmaf(a, s[n], dlh * Bv[n]);
            pp[n] *= a;
        }
    }

    const size_t o = (((size_t)b * NCHUNK + c) * DINNER + d) * NSTATE;
    #pragma unroll
    for (int q = 0; q < 4; ++q) {
        *(f32x4*)(Sbuf + o + q * 4) = (f32x4){s[q*4+0], s[q*4+1], s[q*4+2], s[q*4+3]};
        *(f32x4*)(Pbuf + o + q * 4) = (f32x4){pp[q*4+0], pp[q*4+1], pp[q*4+2], pp[q*4+3]};
    }
}

__global__ __launch_bounds__(256) void scan_p2(
    const float* __restrict__ Pbuf, float* __restrict__ Sbuf)
{
    const int tid = blockIdx.x * 256 + threadIdx.x;
    const int n = tid & 15;
    const int d = (tid >> 4) & (DINNER - 1);
    const int b = tid >> 15;
    const size_t stride = (size_t)DINNER * NSTATE;
    size_t idx = ((size_t)b * NCHUNK * DINNER + d) * NSTATE + n;
    float cin = 0.f;
    for (int c = 0; c < NCHUNK; ++c, idx += stride) {
        float S = Sbuf[idx];
        float P = Pbuf[idx];
        Sbuf[idx] = cin;
        cin = fmaf(P, cin, S);
    }
}

__global__ __launch_bounds__(256) void scan_p3(
    const ushort_t* __restrict__ delta_bf,
    const ushort_t* __restrict__ hb,
    const float* __restrict__ xdbl,
    const ushort_t* __restrict__ xrb,      // res at col 2048+d (bf16)
    const float* __restrict__ Alog,
    const float* __restrict__ Dp,
    const float* __restrict__ Sbuf,
    ushort_t* __restrict__ yb)
{
    const int d  = (blockIdx.x & 7) * 256 + threadIdx.x;
    const int bc = blockIdx.x >> 3;
    const int b  = bc >> 5;
    const int c  = bc & (NCHUNK - 1);
    const int t0 = c * TCHUNK;

    float A[NSTATE];
    #pragma unroll
    for (int q = 0; q < 4; ++q) {
        f32x4 al = *(const f32x4*)(Alog + (size_t)d * NSTATE + q * 4);
        #pragma unroll
        for (int j = 0; j < 4; ++j) A[q * 4 + j] = -expf(al[j]);
    }
    const float Dd = Dp[d];

    float s[NSTATE];
    const size_t o = (((size_t)b * NCHUNK + c) * DINNER + d) * NSTATE;
    #pragma unroll
    for (int q = 0; q < 4; ++q) {
        f32x4 sv = *(const f32x4*)(Sbuf + o + q * 4);
        #pragma unroll
        for (int j = 0; j < 4; ++j) s[q * 4 + j] = sv[j];
    }

    for (int tt = 0; tt < TCHUNK; ++tt) {
        const size_t row = (size_t)(b * SEQ + t0 + tt);
        float dl = bf2f(delta_bf[row * DINNER + d]);
        float hv = bf2f(hb[row * DINNER + d]);
        float rv = bf2f(xrb[row * 4096 + DINNER + d]);
        float dlh = dl * hv;
        float Bv[NSTATE], Cv[NSTATE];
        #pragma unroll
        for (int q = 0; q < 4; ++q) {
            f32x4 bv = *(const f32x4*)(xdbl + row * XDBLW + DTRANK + q * 4);
            f32x4 cv = *(const f32x4*)(xdbl + row * XDBLW + DTRANK + NSTATE + q * 4);
            #pragma unroll
            for (int j = 0; j < 4; ++j) { Bv[q*4+j] = bv[j]; Cv[q*4+j] = cv[j]; }
        }
        float y = 0.f;
        #pragma unroll
        for (int n = 0; n < NSTATE; ++n) {
            float a = expf(dl * A[n]);
            s[n] = fmaf(a, s[n], dlh * Bv[n]);
            y = fmaf(s[n], Cv[n], y);
        }
        y = fmaf(hv, Dd, y);
        float sig = 1.f / (1.f + expf(-rv));
        y *= rv * sig;
        yb[row * DINNER + d] = f2bf(y);
    }
}

extern "C" void kernel_launch(void* const* d_in, const int* in_sizes, int n_in,
                              void* d_out, int out_size, void* d_ws, size_t ws_size,
                              hipStream_t stream)
{
    const float* x     = (const float*)d_in[0];
    const float* Win   = (const float*)d_in[1];
    const float* convw = (const float*)d_in[2];
    const float* convb = (const float*)d_in[3];
    const float* Wxp   = (const float*)d_in[4];
    const float* Wdt   = (const float*)d_in[5];   // 64 x 2048 f32
    const float* dtb   = (const float*)d_in[6];
    const float* Alog  = (const float*)d_in[7];
    const float* Dp    = (const float*)d_in[8];
    const float* Wout  = (const float*)d_in[9];
    float* out = (float*)d_out;

    char* base = (char*)d_ws; size_t off = 0;
    auto alloc = [&](size_t bytes) -> char* {
        char* q = base + off;
        off = (off + bytes + 255) & ~(size_t)255;
        return q;
    };
    ushort_t* WtIn  = (ushort_t*)alloc((size_t)4096 * 1024 * 2);
    ushort_t* WtOut = (ushort_t*)alloc((size_t)1024 * 2048 * 2);
    ushort_t* WtXp  = (ushort_t*)alloc((size_t)96   * 2048 * 2);
    ushort_t* xb    = (ushort_t*)alloc((size_t)BL * DIM * 2);
    ushort_t* xrb   = (ushort_t*)alloc((size_t)BL * 4096 * 2);   // bf16 xp|res
    ushort_t* hb    = (ushort_t*)alloc((size_t)BL * DINNER * 2);
    float*    xdbl  = (float*)   alloc((size_t)BL * XDBLW * 4);
    ushort_t* dltbf = (ushort_t*)alloc((size_t)BL * DINNER * 2);
    ushort_t* yb    = (ushort_t*)alloc((size_t)BL * DINNER * 2);
    float*    Pbuf  = (float*)   alloc((size_t)BATCH * NCHUNK * DINNER * NSTATE * 4);  // 8 MB
    float*    Sbuf  = (float*)   alloc((size_t)BATCH * NCHUNK * DINNER * NSTATE * 4);  // 8 MB
    float*    Ppart = (float*)   alloc((size_t)KSLICE * BL * XDBLW * 4);               // 12.6 MB
    (void)ws_size;

    dim3 tb(32, 8);
    transpose_f32_bf16<<<dim3(4096/32, 1024/32), tb, 0, stream>>>(Win,  WtIn,  1024, 4096);
    transpose_f32_bf16<<<dim3(1024/32, 2048/32), tb, 0, stream>>>(Wout, WtOut, 2048, 1024);
    transpose_f32_bf16<<<dim3(96/32,   2048/32), tb, 0, stream>>>(Wxp,  WtXp,  2048, 96);
    cvt_f32_bf16<<<dim3((BL*DIM/4 + 255)/256), 256, 0, stream>>>(x, xb, BL*DIM);

    // G1: xr = x @ in_proj_w   (2048 x 4096, K=1024) -> bf16
    gemm_lds<<<dim3(4096/128, BL/128), 256, 0, stream>>>(
        xb, DIM, WtIn, DIM, DIM, nullptr, xrb, 2*DINNER);

    conv_silu<<<dim3(DINNER/256, BL), 256, 0, stream>>>(xrb, convw, convb, hb);

    // G2: xdbl = h @ x_proj_w  (2048 x 96, K=2048) via split-K + reduce
    gemm_n96_splitk<<<dim3(KSLICE, BL/128), 256, 0, stream>>>(hb, WtXp, Ppart);
    g2_reduce<<<dim3(BL * 24 / 256), 256, 0, stream>>>(Ppart, xdbl);

    // delta = softplus(dlt @ dt_proj_w + dt_b) -> bf16
    delta_kernel<<<dim3(BL / 4), 256, 0, stream>>>(xdbl, Wdt, dtb, dltbf);

    // chunked parallel scan (NCHUNK=32)
    scan_p1<<<dim3(8 * BATCH * NCHUNK), 256, 0, stream>>>(dltbf, hb, xdbl, Alog, Pbuf, Sbuf);
    scan_p2<<<dim3(BATCH * DINNER * NSTATE / 256), 256, 0, stream>>>(Pbuf, Sbuf);
    scan_p3<<<dim3(8 * BATCH * NCHUNK), 256, 0, stream>>>(dltbf, hb, xdbl, xrb, Alog, Dp, Sbuf, yb);

    // G4: out = y @ out_proj_w (2048 x 1024, K=2048) -> f32 d_out
    gemm_lds<<<dim3(DIM/128, BL/128), 256, 0, stream>>>(
        yb, DINNER, WtOut, DINNER, DINNER, out, nullptr, DIM);
}

// Round 11
// 246.204 us; speedup vs baseline: 1.0001x; 1.0001x over previous
//
#include <hip/hip_runtime.h>
#include <hip/hip_bf16.h>

// ---- problem dims (compile-time) ----
#define DIM     1024
#define DINNER  2048
#define NSTATE  16
#define DTRANK  64
#define DCONV   4
#define BATCH   2
#define SEQ     1024
#define BL      (BATCH*SEQ)     // 2048 rows
#define XDBLW   96              // DTRANK + 2*NSTATE
#define NCHUNK  32
#define TCHUNK  32              // SEQ / NCHUNK
#define KSLICE  16              // split-K factor for G2

typedef __attribute__((ext_vector_type(4))) float  f32x4;
typedef __attribute__((ext_vector_type(8))) short  bf16x8;
typedef unsigned short ushort_t;

__device__ __forceinline__ ushort_t f2bf(float f) {
    union { float f; unsigned int u; } v; v.f = f;
    unsigned int lsb = (v.u >> 16) & 1u;
    v.u += 0x7fffu + lsb;
    return (ushort_t)(v.u >> 16);
}
__device__ __forceinline__ float bf2f(ushort_t h) {
    union { unsigned u; float f; } v; v.u = ((unsigned)h) << 16; return v.f;
}

typedef __attribute__((address_space(1))) unsigned int gu32_t;
typedef __attribute__((address_space(3))) unsigned int lu32_t;
__device__ __forceinline__ void gload_lds16(const ushort_t* g, ushort_t* l) {
    __builtin_amdgcn_global_load_lds((const gu32_t*)(const void*)g,
                                     (lu32_t*)(void*)l, 16, 0, 0);
}

// ================= fused prep: 3 weight transposes + x convert =================
// grid partition: [0,4096) Win-T | [4096,6144) Wout-T | [6144,6336) Wxp-T | [6336,8384) cvt
__global__ __launch_bounds__(256) void prep_fused(
    const float* __restrict__ Win,  ushort_t* __restrict__ WtIn,
    const float* __restrict__ Wout, ushort_t* __restrict__ WtOut,
    const float* __restrict__ Wxp,  ushort_t* __restrict__ WtXp,
    const float* __restrict__ x,    ushort_t* __restrict__ xb)
{
    __shared__ float tile[32][33];
    const int tid = threadIdx.x;
    const int tx = tid & 31, ty = tid >> 5;
    const int bid = blockIdx.x;

    const float* src; ushort_t* dst; int R, C, bx, by;
    if (bid < 4096)      { src = Win;  dst = WtIn;  R = 1024; C = 4096; int j = bid;        bx = j % 128; by = j / 128; }
    else if (bid < 6144) { src = Wout; dst = WtOut; R = 2048; C = 1024; int j = bid - 4096; bx = j % 32;  by = j / 32; }
    else if (bid < 6336) { src = Wxp;  dst = WtXp;  R = 2048; C = 96;   int j = bid - 6144; bx = j % 3;   by = j / 3; }
    else {
        int i = ((bid - 6336) * 256 + tid) * 4;
        f32x4 v = *(const f32x4*)(x + i);
        ushort_t r0 = f2bf(v[0]), r1 = f2bf(v[1]), r2 = f2bf(v[2]), r3 = f2bf(v[3]);
        *(uint2*)(xb + i) = make_uint2((unsigned)r0 | ((unsigned)r1 << 16),
                                       (unsigned)r2 | ((unsigned)r3 << 16));
        return;
    }

    const int r0 = by * 32, c0 = bx * 32;
    #pragma unroll
    for (int i = 0; i < 4; ++i)
        tile[ty + i * 8][tx] = src[(size_t)(r0 + ty + i * 8) * C + c0 + tx];
    __syncthreads();
    #pragma unroll
    for (int i = 0; i < 4; ++i)
        dst[(size_t)(c0 + ty + i * 8) * R + r0 + tx] = f2bf(tile[tx][ty + i * 8]);
}

// ======== m97-style MFMA GEMM: C = A(MxK) * Bt(NxK)^T, full 128-tiles ========
__global__ __launch_bounds__(256) void gemm_lds(
    const ushort_t* __restrict__ A,  int lda,
    const ushort_t* __restrict__ Bt, int ldb,
    int K,
    float* __restrict__ Cf, ushort_t* __restrict__ Cb, int ldc)
{
    __shared__ ushort_t As[128 * 32];
    __shared__ ushort_t Bs[128 * 32];

    const int tid  = threadIdx.x;
    const int m0   = blockIdx.y * 128;
    const int n0   = blockIdx.x * 128;
    const int wid  = tid >> 6;
    const int lane = tid & 63;
    const int wm   = (wid >> 1) * 64;
    const int wn   = (wid & 1) * 64;
    const int lr   = lane & 15;
    const int lk   = (lane >> 4) * 8;

    const int c0 = wid * 64 + lane;
    const int c1 = 256 + c0;
    const int r0 = c0 >> 2, f0 = (c0 & 3) * 8;
    const int r1 = c1 >> 2, f1 = (c1 & 3) * 8;
    ushort_t* lA0 = &As[(wid * 64) * 8];
    ushort_t* lA1 = &As[(256 + wid * 64) * 8];
    ushort_t* lB0 = &Bs[(wid * 64) * 8];
    ushort_t* lB1 = &Bs[(256 + wid * 64) * 8];

    f32x4 acc[4][4];
    #pragma unroll
    for (int m = 0; m < 4; ++m)
        #pragma unroll
        for (int n = 0; n < 4; ++n)
            acc[m][n] = (f32x4){0.f, 0.f, 0.f, 0.f};

    for (int k0 = 0; k0 < K; k0 += 32) {
        gload_lds16(A  + (size_t)(m0 + r0) * lda + k0 + f0, lA0);
        gload_lds16(A  + (size_t)(m0 + r1) * lda + k0 + f1, lA1);
        gload_lds16(Bt + (size_t)(n0 + r0) * ldb + k0 + f0, lB0);
        gload_lds16(Bt + (size_t)(n0 + r1) * ldb + k0 + f1, lB1);
        __syncthreads();

        bf16x8 af[4], bfr[4];
        #pragma unroll
        for (int m = 0; m < 4; ++m)
            af[m] = *(const bf16x8*)(&As[(wm + m * 16 + lr) * 32 + lk]);
        #pragma unroll
        for (int n = 0; n < 4; ++n)
            bfr[n] = *(const bf16x8*)(&Bs[(wn + n * 16 + lr) * 32 + lk]);

        #pragma unroll
        for (int m = 0; m < 4; ++m)
            #pragma unroll
            for (int n = 0; n < 4; ++n)
                acc[m][n] = __builtin_amdgcn_mfma_f32_16x16x32_bf16(af[m], bfr[n], acc[m][n], 0, 0, 0);
        __syncthreads();
    }

    const int rbase = (lane >> 4) * 4;
    #pragma unroll
    for (int m = 0; m < 4; ++m) {
        #pragma unroll
        for (int n = 0; n < 4; ++n) {
            int col = n0 + wn + n * 16 + lr;
            #pragma unroll
            for (int r = 0; r < 4; ++r) {
                int row = m0 + wm + m * 16 + rbase + r;
                float v = acc[m][n][r];
                if (Cf) Cf[(size_t)row * ldc + col] = v;
                if (Cb) Cb[(size_t)row * ldc + col] = f2bf(v);
            }
        }
    }
}

// ======== G2 split-K: Ppart[ks] = A(128-row tile) * Bt(96xK slice)^T ========
__global__ __launch_bounds__(256) void gemm_n96_splitk(
    const ushort_t* __restrict__ A,    // BL x 2048 (hb)
    const ushort_t* __restrict__ Bt,   // 96 x 2048 (WtXp)
    float* __restrict__ Ppart)         // [KSLICE][BL][96]
{
    __shared__ ushort_t As[128 * 40];
    __shared__ ushort_t Bs[96 * 40];

    const int tid   = threadIdx.x;
    const int ks    = blockIdx.x;
    const int m0    = blockIdx.y * 128;
    const int kbase = ks * (DINNER / KSLICE);
    const int wid   = tid >> 6;
    const int lane  = tid & 63;
    const int wm    = wid * 32;
    const int lr    = lane & 15;
    const int lk    = (lane >> 4) * 8;

    f32x4 acc[2][6];
    #pragma unroll
    for (int m = 0; m < 2; ++m)
        #pragma unroll
        for (int n = 0; n < 6; ++n)
            acc[m][n] = (f32x4){0.f, 0.f, 0.f, 0.f};

    for (int k0 = kbase; k0 < kbase + DINNER / KSLICE; k0 += 32) {
        #pragma unroll
        for (int c = 0; c < 2; ++c) {
            int cid = tid + c * 256;
            int row = cid >> 2, ck = (cid & 3) * 8;
            *(uint4*)(&As[row * 40 + ck]) =
                *(const uint4*)(A + (size_t)(m0 + row) * DINNER + k0 + ck);
        }
        {
            int row = tid >> 2, ck = (tid & 3) * 8;
            *(uint4*)(&Bs[row * 40 + ck]) =
                *(const uint4*)(Bt + (size_t)row * DINNER + k0 + ck);
            if (tid < 128) {
                int cid = 256 + tid;
                int row2 = cid >> 2, ck2 = (cid & 3) * 8;
                *(uint4*)(&Bs[row2 * 40 + ck2]) =
                    *(const uint4*)(Bt + (size_t)row2 * DINNER + k0 + ck2);
            }
        }
        __syncthreads();

        bf16x8 af[2], bfr[6];
        #pragma unroll
        for (int m = 0; m < 2; ++m)
            af[m] = *(const bf16x8*)(&As[(wm + m * 16 + lr) * 40 + lk]);
        #pragma unroll
        for (int n = 0; n < 6; ++n)
            bfr[n] = *(const bf16x8*)(&Bs[(n * 16 + lr) * 40 + lk]);

        #pragma unroll
        for (int m = 0; m < 2; ++m)
            #pragma unroll
            for (int n = 0; n < 6; ++n)
                acc[m][n] = __builtin_amdgcn_mfma_f32_16x16x32_bf16(af[m], bfr[n], acc[m][n], 0, 0, 0);
        __syncthreads();
    }

    const int rbase = (lane >> 4) * 4;
    #pragma unroll
    for (int m = 0; m < 2; ++m) {
        #pragma unroll
        for (int n = 0; n < 6; ++n) {
            int col = n * 16 + lr;
            #pragma unroll
            for (int r = 0; r < 4; ++r) {
                int row = m0 + wm + m * 16 + rbase + r;
                Ppart[((size_t)ks * BL + row) * XDBLW + col] = acc[m][n][r];
            }
        }
    }
}

// ======== fused: split-K reduce + delta = softplus(dlt@Wdt + dtb) -> bf16 ========
// Block = 4 rows. Phase A: reduce Ppart -> dlt in LDS (cols 0-63) + xdbl (cols 64-95).
// Phase B: delta dot with f32x4 W loads; thread covers d = tid*4..+3 and +1024.
__global__ __launch_bounds__(256, 4) void g2delta(
    const float* __restrict__ Ppart,  // [KSLICE][BL][96]
    const float* __restrict__ Wdt,    // 64 x 2048 f32
    const float* __restrict__ dtb,    // 2048
    float* __restrict__ xdbl,         // BL x 96 (only cols 64..95 written)
    ushort_t* __restrict__ delta_bf)  // BL x 2048 bf16
{
    __shared__ float dltS[4][DTRANK];  // 1 KB
    const int tid = threadIdx.x;
    const int r0  = blockIdx.x * 4;

    if (tid < 96) {
        int r = tid / 24, cg = tid % 24;
        f32x4 s = (f32x4){0.f, 0.f, 0.f, 0.f};
        #pragma unroll
        for (int ks = 0; ks < KSLICE; ++ks)
            s += *(const f32x4*)(Ppart + ((size_t)ks * BL + r0 + r) * XDBLW + cg * 4);
        if (cg < 16) *(f32x4*)&dltS[r][cg * 4] = s;
        else         *(f32x4*)(xdbl + (size_t)(r0 + r) * XDBLW + cg * 4) = s;
    }
    __syncthreads();

    const int d0 = tid * 4;            // 0..1023
    f32x4 a00, a01, a10, a11, a20, a21, a30, a31;
    {
        f32x4 b0 = *(const f32x4*)(dtb + d0);
        f32x4 b1 = *(const f32x4*)(dtb + d0 + 1024);
        a00 = b0; a01 = b1; a10 = b0; a11 = b1;
        a20 = b0; a21 = b1; a30 = b0; a31 = b1;
    }

    #pragma unroll 4
    for (int kq = 0; kq < 16; ++kq) {
        f32x4 dv0 = *(const f32x4*)&dltS[0][kq * 4];
        f32x4 dv1 = *(const f32x4*)&dltS[1][kq * 4];
        f32x4 dv2 = *(const f32x4*)&dltS[2][kq * 4];
        f32x4 dv3 = *(const f32x4*)&dltS[3][kq * 4];
        #pragma unroll
        for (int kk = 0; kk < 4; ++kk) {
            const float* wrow = Wdt + (size_t)(kq * 4 + kk) * DINNER + d0;
            f32x4 w0 = *(const f32x4*)(wrow);
            f32x4 w1 = *(const f32x4*)(wrow + 1024);
            a00 += dv0[kk] * w0; a01 += dv0[kk] * w1;
            a10 += dv1[kk] * w0; a11 += dv1[kk] * w1;
            a20 += dv2[kk] * w0; a21 += dv2[kk] * w1;
            a30 += dv3[kk] * w0; a31 += dv3[kk] * w1;
        }
    }

    #pragma unroll
    for (int r = 0; r < 4; ++r) {
        f32x4 v0 = (r == 0) ? a00 : (r == 1) ? a10 : (r == 2) ? a20 : a30;
        f32x4 v1 = (r == 0) ? a01 : (r == 1) ? a11 : (r == 2) ? a21 : a31;
        ushort_t o0[4], o1[4];
        #pragma unroll
        for (int j = 0; j < 4; ++j) {
            float s0 = v0[j]; s0 = (s0 > 20.f) ? s0 : log1pf(expf(s0));
            float s1 = v1[j]; s1 = (s1 > 20.f) ? s1 : log1pf(expf(s1));
            o0[j] = f2bf(s0); o1[j] = f2bf(s1);
        }
        size_t rowb = (size_t)(r0 + r) * DINNER;
        *(uint2*)(delta_bf + rowb + d0) = make_uint2(
            (unsigned)o0[0] | ((unsigned)o0[1] << 16), (unsigned)o0[2] | ((unsigned)o0[3] << 16));
        *(uint2*)(delta_bf + rowb + d0 + 1024) = make_uint2(
            (unsigned)o1[0] | ((unsigned)o1[1] << 16), (unsigned)o1[2] | ((unsigned)o1[3] << 16));
    }
}

// ---------------- depthwise causal conv(4) + bias + SiLU (bf16 in/out) ----------------
__global__ __launch_bounds__(256) void conv_silu(
    const ushort_t* __restrict__ xrb,   // BL x 4096 bf16 (xp = cols [0,2048))
    const float* __restrict__ convw,
    const float* __restrict__ convb,
    ushort_t* __restrict__ hb)          // BL x 2048 bf16
{
    const int d  = blockIdx.x * 256 + threadIdx.x;
    const int bt = blockIdx.y;
    const int t  = bt & (SEQ - 1);

    float acc = convb[d];
    #pragma unroll
    for (int j = 0; j < DCONV; ++j) {
        int tt = t + j - (DCONV - 1);
        if (tt >= 0)
            acc += convw[d * DCONV + j] * bf2f(xrb[(size_t)(bt + j - (DCONV - 1)) * 4096 + d]);
    }
    float h = acc / (1.f + expf(-acc));
    hb[(size_t)bt * DINNER + d] = f2bf(h);
}

// ================= chunked parallel selective scan =================
__global__ __launch_bounds__(256) void scan_p1(
    const ushort_t* __restrict__ delta_bf,
    const ushort_t* __restrict__ hb,
    const float* __restrict__ xdbl,
    const float* __restrict__ Alog,
    float* __restrict__ Pbuf,
    float* __restrict__ Sbuf)
{
    const int d  = (blockIdx.x & 7) * 256 + threadIdx.x;
    const int bc = blockIdx.x >> 3;
    const int b  = bc >> 5;
    const int c  = bc & (NCHUNK - 1);
    const int t0 = c * TCHUNK;

    float A[NSTATE];
    #pragma unroll
    for (int q = 0; q < 4; ++q) {
        f32x4 al = *(const f32x4*)(Alog + (size_t)d * NSTATE + q * 4);
        #pragma unroll
        for (int j = 0; j < 4; ++j) A[q * 4 + j] = -expf(al[j]);
    }

    float s[NSTATE], pp[NSTATE];
    #pragma unroll
    for (int n = 0; n < NSTATE; ++n) { s[n] = 0.f; pp[n] = 1.f; }

    for (int tt = 0; tt < TCHUNK; ++tt) {
        const size_t row = (size_t)(b * SEQ + t0 + tt);
        float dl = bf2f(delta_bf[row * DINNER + d]);
        float hv = bf2f(hb[row * DINNER + d]);
        float dlh = dl * hv;
        float Bv[NSTATE];
        #pragma unroll
        for (int q = 0; q < 4; ++q) {
            f32x4 bv = *(const f32x4*)(xdbl + row * XDBLW + DTRANK + q * 4);
            #pragma unroll
            for (int j = 0; j < 4; ++j) Bv[q * 4 + j] = bv[j];
        }
        #pragma unroll
        for (int n = 0; n < NSTATE; ++n) {
            float a = expf(dl * A[n]);
            s[n]  = fmaf(a, s[n], dlh * Bv[n]);
            pp[n] *= a;
        }
    }

    const size_t o = (((size_t)b * NCHUNK + c) * DINNER + d) * NSTATE;
    #pragma unroll
    for (int q = 0; q < 4; ++q) {
        *(f32x4*)(Sbuf + o + q * 4) = (f32x4){s[q*4+0], s[q*4+1], s[q*4+2], s[q*4+3]};
        *(f32x4*)(Pbuf + o + q * 4) = (f32x4){pp[q*4+0], pp[q*4+1], pp[q*4+2], pp[q*4+3]};
    }
}

__global__ __launch_bounds__(256) void scan_p2(
    const float* __restrict__ Pbuf, float* __restrict__ Sbuf)
{
    const int tid = blockIdx.x * 256 + threadIdx.x;
    const int n = tid & 15;
    const int d = (tid >> 4) & (DINNER - 1);
    const int b = tid >> 15;
    const size_t stride = (size_t)DINNER * NSTATE;
    size_t idx = ((size_t)b * NCHUNK * DINNER + d) * NSTATE + n;
    float cin = 0.f;
    for (int c = 0; c < NCHUNK; ++c, idx += stride) {
        float S = Sbuf[idx];
        float P = Pbuf[idx];
        Sbuf[idx] = cin;
        cin = fmaf(P, cin, S);
    }
}

__global__ __launch_bounds__(256) void scan_p3(
    const ushort_t* __restrict__ delta_bf,
    const ushort_t* __restrict__ hb,
    const float* __restrict__ xdbl,
    const ushort_t* __restrict__ xrb,      // res at col 2048+d (bf16)
    const float* __restrict__ Alog,
    const float* __restrict__ Dp,
    const float* __restrict__ Sbuf,
    ushort_t* __restrict__ yb)
{
    const int d  = (blockIdx.x & 7) * 256 + threadIdx.x;
    const int bc = blockIdx.x >> 3;
    const int b  = bc >> 5;
    const int c  = bc & (NCHUNK - 1);
    const int t0 = c * TCHUNK;

    float A[NSTATE];
    #pragma unroll
    for (int q = 0; q < 4; ++q) {
        f32x4 al = *(const f32x4*)(Alog + (size_t)d * NSTATE + q * 4);
        #pragma unroll
        for (int j = 0; j < 4; ++j) A[q * 4 + j] = -expf(al[j]);
    }
    const float Dd = Dp[d];

    float s[NSTATE];
    const size_t o = (((size_t)b * NCHUNK + c) * DINNER + d) * NSTATE;
    #pragma unroll
    for (int q = 0; q < 4; ++q) {
        f32x4 sv = *(const f32x4*)(Sbuf + o + q * 4);
        #pragma unroll
        for (int j = 0; j < 4; ++j) s[q * 4 + j] = sv[j];
    }

    for (int tt = 0; tt < TCHUNK; ++tt) {
        const size_t row = (size_t)(b * SEQ + t0 + tt);
        float dl = bf2f(delta_bf[row * DINNER + d]);
        float hv = bf2f(hb[row * DINNER + d]);
        float rv = bf2f(xrb[row * 4096 + DINNER + d]);
        float dlh = dl * hv;
        float Bv[NSTATE], Cv[NSTATE];
        #pragma unroll
        for (int q = 0; q < 4; ++q) {
            f32x4 bv = *(const f32x4*)(xdbl + row * XDBLW + DTRANK + q * 4);
            f32x4 cv = *(const f32x4*)(xdbl + row * XDBLW + DTRANK + NSTATE + q * 4);
            #pragma unroll
            for (int j = 0; j < 4; ++j) { Bv[q*4+j] = bv[j]; Cv[q*4+j] = cv[j]; }
        }
        float y = 0.f;
        #pragma unroll
        for (int n = 0; n < NSTATE; ++n) {
            float a = expf(dl * A[n]);
            s[n] = fmaf(a, s[n], dlh * Bv[n]);
            y = fmaf(s[n], Cv[n], y);
        }
        y = fmaf(hv, Dd, y);
        float sig = 1.f / (1.f + expf(-rv));
        y *= rv * sig;
        yb[row * DINNER + d] = f2bf(y);
    }
}

extern "C" void kernel_launch(void* const* d_in, const int* in_sizes, int n_in,
                              void* d_out, int out_size, void* d_ws, size_t ws_size,
                              hipStream_t stream)
{
    const float* x     = (const float*)d_in[0];
    const float* Win   = (const float*)d_in[1];
    const float* convw = (const float*)d_in[2];
    const float* convb = (const float*)d_in[3];
    const float* Wxp   = (const float*)d_in[4];
    const float* Wdt   = (const float*)d_in[5];   // 64 x 2048 f32
    const float* dtb   = (const float*)d_in[6];
    const float* Alog  = (const float*)d_in[7];
    const float* Dp    = (const float*)d_in[8];
    const float* Wout  = (const float*)d_in[9];
    float* out = (float*)d_out;

    char* base = (char*)d_ws; size_t off = 0;
    auto alloc = [&](size_t bytes) -> char* {
        char* q = base + off;
        off = (off + bytes + 255) & ~(size_t)255;
        return q;
    };
    ushort_t* WtIn  = (ushort_t*)alloc((size_t)4096 * 1024 * 2);
    ushort_t* WtOut = (ushort_t*)alloc((size_t)1024 * 2048 * 2);
    ushort_t* WtXp  = (ushort_t*)alloc((size_t)96   * 2048 * 2);
    ushort_t* xb    = (ushort_t*)alloc((size_t)BL * DIM * 2);
    ushort_t* xrb   = (ushort_t*)alloc((size_t)BL * 4096 * 2);   // bf16 xp|res
    ushort_t* hb    = (ushort_t*)alloc((size_t)BL * DINNER * 2);
    float*    xdbl  = (float*)   alloc((size_t)BL * XDBLW * 4);
    ushort_t* dltbf = (ushort_t*)alloc((size_t)BL * DINNER * 2);
    ushort_t* yb    = (ushort_t*)alloc((size_t)BL * DINNER * 2);
    float*    Pbuf  = (float*)   alloc((size_t)BATCH * NCHUNK * DINNER * NSTATE * 4);  // 8 MB
    float*    Sbuf  = (float*)   alloc((size_t)BATCH * NCHUNK * DINNER * NSTATE * 4);  // 8 MB
    float*    Ppart = (float*)   alloc((size_t)KSLICE * BL * XDBLW * 4);               // 12.6 MB
    (void)ws_size;

    // fused prep: 3 transposes + x->bf16 (1 launch instead of 4)
    prep_fused<<<dim3(8384), 256, 0, stream>>>(Win, WtIn, Wout, WtOut, Wxp, WtXp, x, xb);

    // G1: xr = x @ in_proj_w   (2048 x 4096, K=1024) -> bf16
    gemm_lds<<<dim3(4096/128, BL/128), 256, 0, stream>>>(
        xb, DIM, WtIn, DIM, DIM, nullptr, xrb, 2*DINNER);

    conv_silu<<<dim3(DINNER/256, BL), 256, 0, stream>>>(xrb, convw, convb, hb);

    // G2: xdbl partials (split-K)
    gemm_n96_splitk<<<dim3(KSLICE, BL/128), 256, 0, stream>>>(hb, WtXp, Ppart);

    // fused: reduce partials + delta (softplus(dlt@Wdt+dtb)) -> xdbl(B,C) + bf16 delta
    g2delta<<<dim3(BL / 4), 256, 0, stream>>>(Ppart, Wdt, dtb, xdbl, dltbf);

    // chunked parallel scan (NCHUNK=32)
    scan_p1<<<dim3(8 * BATCH * NCHUNK), 256, 0, stream>>>(dltbf, hb, xdbl, Alog, Pbuf, Sbuf);
    scan_p2<<<dim3(BATCH * DINNER * NSTATE / 256), 256, 0, stream>>>(Pbuf, Sbuf);
    scan_p3<<<dim3(8 * BATCH * NCHUNK), 256, 0, stream>>>(dltbf, hb, xdbl, xrb, Alog, Dp, Sbuf, yb);

    // G4: out = y @ out_proj_w (2048 x 1024, K=2048) -> f32 d_out
    gemm_lds<<<dim3(DIM/128, BL/128), 256, 0, stream>>>(
        yb, DINNER, WtOut, DINNER, DINNER, out, nullptr, DIM);
}

// Round 12
// 238.250 us; speedup vs baseline: 1.0335x; 1.0334x over previous
//
#include <hip/hip_runtime.h>
#include <hip/hip_bf16.h>

// ---- problem dims (compile-time) ----
#define DIM     1024
#define DINNER  2048
#define NSTATE  16
#define DTRANK  64
#define DCONV   4
#define BATCH   2
#define SEQ     1024
#define BL      (BATCH*SEQ)     // 2048 rows
#define XDBLW   96              // DTRANK + 2*NSTATE
#define NCHUNK  32
#define TCHUNK  32              // SEQ / NCHUNK
#define KSLICE  16              // split-K factor for G2

typedef __attribute__((ext_vector_type(4))) float  f32x4;
typedef __attribute__((ext_vector_type(8))) short  bf16x8;
typedef unsigned short ushort_t;

__device__ __forceinline__ ushort_t f2bf(float f) {
    union { float f; unsigned int u; } v; v.f = f;
    unsigned int lsb = (v.u >> 16) & 1u;
    v.u += 0x7fffu + lsb;
    return (ushort_t)(v.u >> 16);
}
__device__ __forceinline__ float bf2f(ushort_t h) {
    union { unsigned u; float f; } v; v.u = ((unsigned)h) << 16; return v.f;
}

typedef __attribute__((address_space(1))) unsigned int gu32_t;
typedef __attribute__((address_space(3))) unsigned int lu32_t;
__device__ __forceinline__ void gload_lds16(const ushort_t* g, ushort_t* l) {
    __builtin_amdgcn_global_load_lds((const gu32_t*)(const void*)g,
                                     (lu32_t*)(void*)l, 16, 0, 0);
}

// ================= fused prep: 3 weight transposes + x convert =================
__global__ __launch_bounds__(256) void prep_fused(
    const float* __restrict__ Win,  ushort_t* __restrict__ WtIn,
    const float* __restrict__ Wout, ushort_t* __restrict__ WtOut,
    const float* __restrict__ Wxp,  ushort_t* __restrict__ WtXp,
    const float* __restrict__ x,    ushort_t* __restrict__ xb)
{
    __shared__ float tile[32][33];
    const int tid = threadIdx.x;
    const int tx = tid & 31, ty = tid >> 5;
    const int bid = blockIdx.x;

    const float* src; ushort_t* dst; int R, C, bx, by;
    if (bid < 4096)      { src = Win;  dst = WtIn;  R = 1024; C = 4096; int j = bid;        bx = j % 128; by = j / 128; }
    else if (bid < 6144) { src = Wout; dst = WtOut; R = 2048; C = 1024; int j = bid - 4096; bx = j % 32;  by = j / 32; }
    else if (bid < 6336) { src = Wxp;  dst = WtXp;  R = 2048; C = 96;   int j = bid - 6144; bx = j % 3;   by = j / 3; }
    else {
        int i = ((bid - 6336) * 256 + tid) * 4;
        f32x4 v = *(const f32x4*)(x + i);
        ushort_t r0 = f2bf(v[0]), r1 = f2bf(v[1]), r2 = f2bf(v[2]), r3 = f2bf(v[3]);
        *(uint2*)(xb + i) = make_uint2((unsigned)r0 | ((unsigned)r1 << 16),
                                       (unsigned)r2 | ((unsigned)r3 << 16));
        return;
    }

    const int r0 = by * 32, c0 = bx * 32;
    #pragma unroll
    for (int i = 0; i < 4; ++i)
        tile[ty + i * 8][tx] = src[(size_t)(r0 + ty + i * 8) * C + c0 + tx];
    __syncthreads();
    #pragma unroll
    for (int i = 0; i < 4; ++i)
        dst[(size_t)(c0 + ty + i * 8) * R + r0 + tx] = f2bf(tile[tx][ty + i * 8]);
}

// ======== m97-style MFMA GEMM: C = A(MxK) * Bt(NxK)^T, full 128-tiles ========
__global__ __launch_bounds__(256) void gemm_lds(
    const ushort_t* __restrict__ A,  int lda,
    const ushort_t* __restrict__ Bt, int ldb,
    int K,
    float* __restrict__ Cf, ushort_t* __restrict__ Cb, int ldc)
{
    __shared__ ushort_t As[128 * 32];
    __shared__ ushort_t Bs[128 * 32];

    const int tid  = threadIdx.x;
    const int m0   = blockIdx.y * 128;
    const int n0   = blockIdx.x * 128;
    const int wid  = tid >> 6;
    const int lane = tid & 63;
    const int wm   = (wid >> 1) * 64;
    const int wn   = (wid & 1) * 64;
    const int lr   = lane & 15;
    const int lk   = (lane >> 4) * 8;

    const int c0 = wid * 64 + lane;
    const int c1 = 256 + c0;
    const int r0 = c0 >> 2, f0 = (c0 & 3) * 8;
    const int r1 = c1 >> 2, f1 = (c1 & 3) * 8;
    ushort_t* lA0 = &As[(wid * 64) * 8];
    ushort_t* lA1 = &As[(256 + wid * 64) * 8];
    ushort_t* lB0 = &Bs[(wid * 64) * 8];
    ushort_t* lB1 = &Bs[(256 + wid * 64) * 8];

    f32x4 acc[4][4];
    #pragma unroll
    for (int m = 0; m < 4; ++m)
        #pragma unroll
        for (int n = 0; n < 4; ++n)
            acc[m][n] = (f32x4){0.f, 0.f, 0.f, 0.f};

    for (int k0 = 0; k0 < K; k0 += 32) {
        gload_lds16(A  + (size_t)(m0 + r0) * lda + k0 + f0, lA0);
        gload_lds16(A  + (size_t)(m0 + r1) * lda + k0 + f1, lA1);
        gload_lds16(Bt + (size_t)(n0 + r0) * ldb + k0 + f0, lB0);
        gload_lds16(Bt + (size_t)(n0 + r1) * ldb + k0 + f1, lB1);
        __syncthreads();

        bf16x8 af[4], bfr[4];
        #pragma unroll
        for (int m = 0; m < 4; ++m)
            af[m] = *(const bf16x8*)(&As[(wm + m * 16 + lr) * 32 + lk]);
        #pragma unroll
        for (int n = 0; n < 4; ++n)
            bfr[n] = *(const bf16x8*)(&Bs[(wn + n * 16 + lr) * 32 + lk]);

        #pragma unroll
        for (int m = 0; m < 4; ++m)
            #pragma unroll
            for (int n = 0; n < 4; ++n)
                acc[m][n] = __builtin_amdgcn_mfma_f32_16x16x32_bf16(af[m], bfr[n], acc[m][n], 0, 0, 0);
        __syncthreads();
    }

    const int rbase = (lane >> 4) * 4;
    #pragma unroll
    for (int m = 0; m < 4; ++m) {
        #pragma unroll
        for (int n = 0; n < 4; ++n) {
            int col = n0 + wn + n * 16 + lr;
            #pragma unroll
            for (int r = 0; r < 4; ++r) {
                int row = m0 + wm + m * 16 + rbase + r;
                float v = acc[m][n][r];
                if (Cf) Cf[(size_t)row * ldc + col] = v;
                if (Cb) Cb[(size_t)row * ldc + col] = f2bf(v);
            }
        }
    }
}

// ======== G2 split-K: Ppart[ks] = A(128-row tile) * Bt(96xK slice)^T ========
__global__ __launch_bounds__(256) void gemm_n96_splitk(
    const ushort_t* __restrict__ A,    // BL x 2048 (hb)
    const ushort_t* __restrict__ Bt,   // 96 x 2048 (WtXp)
    float* __restrict__ Ppart)         // [KSLICE][BL][96]
{
    __shared__ ushort_t As[128 * 40];
    __shared__ ushort_t Bs[96 * 40];

    const int tid   = threadIdx.x;
    const int ks    = blockIdx.x;
    const int m0    = blockIdx.y * 128;
    const int kbase = ks * (DINNER / KSLICE);
    const int wid   = tid >> 6;
    const int lane  = tid & 63;
    const int wm    = wid * 32;
    const int lr    = lane & 15;
    const int lk    = (lane >> 4) * 8;

    f32x4 acc[2][6];
    #pragma unroll
    for (int m = 0; m < 2; ++m)
        #pragma unroll
        for (int n = 0; n < 6; ++n)
            acc[m][n] = (f32x4){0.f, 0.f, 0.f, 0.f};

    for (int k0 = kbase; k0 < kbase + DINNER / KSLICE; k0 += 32) {
        #pragma unroll
        for (int c = 0; c < 2; ++c) {
            int cid = tid + c * 256;
            int row = cid >> 2, ck = (cid & 3) * 8;
            *(uint4*)(&As[row * 40 + ck]) =
                *(const uint4*)(A + (size_t)(m0 + row) * DINNER + k0 + ck);
        }
        {
            int row = tid >> 2, ck = (tid & 3) * 8;
            *(uint4*)(&Bs[row * 40 + ck]) =
                *(const uint4*)(Bt + (size_t)row * DINNER + k0 + ck);
            if (tid < 128) {
                int cid = 256 + tid;
                int row2 = cid >> 2, ck2 = (cid & 3) * 8;
                *(uint4*)(&Bs[row2 * 40 + ck2]) =
                    *(const uint4*)(Bt + (size_t)row2 * DINNER + k0 + ck2);
            }
        }
        __syncthreads();

        bf16x8 af[2], bfr[6];
        #pragma unroll
        for (int m = 0; m < 2; ++m)
            af[m] = *(const bf16x8*)(&As[(wm + m * 16 + lr) * 40 + lk]);
        #pragma unroll
        for (int n = 0; n < 6; ++n)
            bfr[n] = *(const bf16x8*)(&Bs[(n * 16 + lr) * 40 + lk]);

        #pragma unroll
        for (int m = 0; m < 2; ++m)
            #pragma unroll
            for (int n = 0; n < 6; ++n)
                acc[m][n] = __builtin_amdgcn_mfma_f32_16x16x32_bf16(af[m], bfr[n], acc[m][n], 0, 0, 0);
        __syncthreads();
    }

    const int rbase = (lane >> 4) * 4;
    #pragma unroll
    for (int m = 0; m < 2; ++m) {
        #pragma unroll
        for (int n = 0; n < 6; ++n) {
            int col = n * 16 + lr;
            #pragma unroll
            for (int r = 0; r < 4; ++r) {
                int row = m0 + wm + m * 16 + rbase + r;
                Ppart[((size_t)ks * BL + row) * XDBLW + col] = acc[m][n][r];
            }
        }
    }
}

// reduce split-K partials -> xdbl (f32, all 96 cols)
__global__ __launch_bounds__(256) void g2_reduce(
    const float* __restrict__ Ppart, float* __restrict__ xdbl)
{
    int idx = blockIdx.x * 256 + threadIdx.x;
    int row = idx / 24, cg = (idx % 24) * 4;
    f32x4 s = (f32x4){0.f, 0.f, 0.f, 0.f};
    #pragma unroll
    for (int ks = 0; ks < KSLICE; ++ks)
        s += *(const f32x4*)(Ppart + ((size_t)ks * BL + row) * XDBLW + cg);
    *(f32x4*)(xdbl + (size_t)row * XDBLW + cg) = s;
}

// ======== delta_v5: block = 32 rows x 256-d slice, W tile in LDS once ========
// LDS: W 64x256 f32 (64 KB) + dlt 32x64 f32 (8 KB) = 72 KB -> 2 blocks/CU.
// Wave w -> rows w*8..w*8+7; lane -> d = {lane, lane+64, lane+128, lane+192}
// (stride-1 b32 W reads: 2-way bank alias = free; dlt reads broadcast b128).
__global__ __launch_bounds__(256, 4) void delta_v5(
    const float* __restrict__ xdbl,   // BL x 96, dlt = cols [0,64)
    const float* __restrict__ Wdt,    // 64 x 2048 f32
    const float* __restrict__ dtb,    // 2048
    ushort_t* __restrict__ delta_bf)  // BL x 2048 bf16
{
    __shared__ float WS[64][256];     // 64 KB
    __shared__ float dS[32][64];      // 8 KB
    const int tid  = threadIdx.x;
    const int d0   = (blockIdx.x & 7) * 256;
    const int row0 = (blockIdx.x >> 3) * 32;

    // stage W tile: 4096 f32x4 chunks, bulk coalesced (16 per thread)
    #pragma unroll
    for (int i = 0; i < 16; ++i) {
        int c = i * 256 + tid;
        int k = c >> 6, co = (c & 63) * 4;
        *(f32x4*)&WS[k][co] = *(const f32x4*)(Wdt + (size_t)k * DINNER + d0 + co);
    }
    // stage dlt: 512 chunks (2 per thread)
    #pragma unroll
    for (int i = 0; i < 2; ++i) {
        int c = i * 256 + tid;
        int r = c >> 4, co = (c & 15) * 4;
        *(f32x4*)&dS[r][co] = *(const f32x4*)(xdbl + (size_t)(row0 + r) * XDBLW + co);
    }
    __syncthreads();

    const int w    = tid >> 6;
    const int lane = tid & 63;

    f32x4 acc[8];
    {
        f32x4 bb;
        bb[0] = dtb[d0 + lane];
        bb[1] = dtb[d0 + lane + 64];
        bb[2] = dtb[d0 + lane + 128];
        bb[3] = dtb[d0 + lane + 192];
        #pragma unroll
        for (int r = 0; r < 8; ++r) acc[r] = bb;
    }

    for (int kq = 0; kq < 16; ++kq) {
        f32x4 dv[8];
        #pragma unroll
        for (int r = 0; r < 8; ++r)
            dv[r] = *(const f32x4*)&dS[w * 8 + r][kq * 4];   // wave-uniform broadcast
        #pragma unroll
        for (int kk = 0; kk < 4; ++kk) {
            const int k = kq * 4 + kk;
            float w0 = WS[k][lane];
            float w1 = WS[k][lane + 64];
            float w2 = WS[k][lane + 128];
            float w3 = WS[k][lane + 192];
            #pragma unroll
            for (int r = 0; r < 8; ++r) {
                float dk = dv[r][kk];
                acc[r][0] = fmaf(dk, w0, acc[r][0]);
                acc[r][1] = fmaf(dk, w1, acc[r][1]);
                acc[r][2] = fmaf(dk, w2, acc[r][2]);
                acc[r][3] = fmaf(dk, w3, acc[r][3]);
            }
        }
    }

    #pragma unroll
    for (int r = 0; r < 8; ++r) {
        const size_t rowb = (size_t)(row0 + w * 8 + r) * DINNER + d0;
        f32x4 v = acc[r];
        #pragma unroll
        for (int j = 0; j < 4; ++j) {
            float s = v[j];
            s = (s > 20.f) ? s : log1pf(expf(s));
            delta_bf[rowb + lane + j * 64] = f2bf(s);
        }
    }
}

// ---------------- depthwise causal conv(4) + bias + SiLU (bf16 in/out) ----------------
__global__ __launch_bounds__(256) void conv_silu(
    const ushort_t* __restrict__ xrb,   // BL x 4096 bf16 (xp = cols [0,2048))
    const float* __restrict__ convw,
    const float* __restrict__ convb,
    ushort_t* __restrict__ hb)          // BL x 2048 bf16
{
    const int d  = blockIdx.x * 256 + threadIdx.x;
    const int bt = blockIdx.y;
    const int t  = bt & (SEQ - 1);

    float acc = convb[d];
    #pragma unroll
    for (int j = 0; j < DCONV; ++j) {
        int tt = t + j - (DCONV - 1);
        if (tt >= 0)
            acc += convw[d * DCONV + j] * bf2f(xrb[(size_t)(bt + j - (DCONV - 1)) * 4096 + d]);
    }
    float h = acc / (1.f + expf(-acc));
    hb[(size_t)bt * DINNER + d] = f2bf(h);
}

// ================= chunked parallel selective scan =================
__global__ __launch_bounds__(256) void scan_p1(
    const ushort_t* __restrict__ delta_bf,
    const ushort_t* __restrict__ hb,
    const float* __restrict__ xdbl,
    const float* __restrict__ Alog,
    float* __restrict__ Pbuf,
    float* __restrict__ Sbuf)
{
    const int d  = (blockIdx.x & 7) * 256 + threadIdx.x;
    const int bc = blockIdx.x >> 3;
    const int b  = bc >> 5;
    const int c  = bc & (NCHUNK - 1);
    const int t0 = c * TCHUNK;

    float A[NSTATE];
    #pragma unroll
    for (int q = 0; q < 4; ++q) {
        f32x4 al = *(const f32x4*)(Alog + (size_t)d * NSTATE + q * 4);
        #pragma unroll
        for (int j = 0; j < 4; ++j) A[q * 4 + j] = -expf(al[j]);
    }

    float s[NSTATE], pp[NSTATE];
    #pragma unroll
    for (int n = 0; n < NSTATE; ++n) { s[n] = 0.f; pp[n] = 1.f; }

    for (int tt = 0; tt < TCHUNK; ++tt) {
        const size_t row = (size_t)(b * SEQ + t0 + tt);
        float dl = bf2f(delta_bf[row * DINNER + d]);
        float hv = bf2f(hb[row * DINNER + d]);
        float dlh = dl * hv;
        float Bv[NSTATE];
        #pragma unroll
        for (int q = 0; q < 4; ++q) {
            f32x4 bv = *(const f32x4*)(xdbl + row * XDBLW + DTRANK + q * 4);
            #pragma unroll
            for (int j = 0; j < 4; ++j) Bv[q * 4 + j] = bv[j];
        }
        #pragma unroll
        for (int n = 0; n < NSTATE; ++n) {
            float a = expf(dl * A[n]);
            s[n]  = fmaf(a, s[n], dlh * Bv[n]);
            pp[n] *= a;
        }
    }

    const size_t o = (((size_t)b * NCHUNK + c) * DINNER + d) * NSTATE;
    #pragma unroll
    for (int q = 0; q < 4; ++q) {
        *(f32x4*)(Sbuf + o + q * 4) = (f32x4){s[q*4+0], s[q*4+1], s[q*4+2], s[q*4+3]};
        *(f32x4*)(Pbuf + o + q * 4) = (f32x4){pp[q*4+0], pp[q*4+1], pp[q*4+2], pp[q*4+3]};
    }
}

__global__ __launch_bounds__(256) void scan_p2(
    const float* __restrict__ Pbuf, float* __restrict__ Sbuf)
{
    const int tid = blockIdx.x * 256 + threadIdx.x;
    const int n = tid & 15;
    const int d = (tid >> 4) & (DINNER - 1);
    const int b = tid >> 15;
    const size_t stride = (size_t)DINNER * NSTATE;
    size_t idx = ((size_t)b * NCHUNK * DINNER + d) * NSTATE + n;
    float cin = 0.f;
    for (int c = 0; c < NCHUNK; ++c, idx += stride) {
        float S = Sbuf[idx];
        float P = Pbuf[idx];
        Sbuf[idx] = cin;
        cin = fmaf(P, cin, S);
    }
}

__global__ __launch_bounds__(256) void scan_p3(
    const ushort_t* __restrict__ delta_bf,
    const ushort_t* __restrict__ hb,
    const float* __restrict__ xdbl,
    const ushort_t* __restrict__ xrb,      // res at col 2048+d (bf16)
    const float* __restrict__ Alog,
    const float* __restrict__ Dp,
    const float* __restrict__ Sbuf,
    ushort_t* __restrict__ yb)
{
    const int d  = (blockIdx.x & 7) * 256 + threadIdx.x;
    const int bc = blockIdx.x >> 3;
    const int b  = bc >> 5;
    const int c  = bc & (NCHUNK - 1);
    const int t0 = c * TCHUNK;

    float A[NSTATE];
    #pragma unroll
    for (int q = 0; q < 4; ++q) {
        f32x4 al = *(const f32x4*)(Alog + (size_t)d * NSTATE + q * 4);
        #pragma unroll
        for (int j = 0; j < 4; ++j) A[q * 4 + j] = -expf(al[j]);
    }
    const float Dd = Dp[d];

    float s[NSTATE];
    const size_t o = (((size_t)b * NCHUNK + c) * DINNER + d) * NSTATE;
    #pragma unroll
    for (int q = 0; q < 4; ++q) {
        f32x4 sv = *(const f32x4*)(Sbuf + o + q * 4);
        #pragma unroll
        for (int j = 0; j < 4; ++j) s[q * 4 + j] = sv[j];
    }

    for (int tt = 0; tt < TCHUNK; ++tt) {
        const size_t row = (size_t)(b * SEQ + t0 + tt);
        float dl = bf2f(delta_bf[row * DINNER + d]);
        float hv = bf2f(hb[row * DINNER + d]);
        float rv = bf2f(xrb[row * 4096 + DINNER + d]);
        float dlh = dl * hv;
        float Bv[NSTATE], Cv[NSTATE];
        #pragma unroll
        for (int q = 0; q < 4; ++q) {
            f32x4 bv = *(const f32x4*)(xdbl + row * XDBLW + DTRANK + q * 4);
            f32x4 cv = *(const f32x4*)(xdbl + row * XDBLW + DTRANK + NSTATE + q * 4);
            #pragma unroll
            for (int j = 0; j < 4; ++j) { Bv[q*4+j] = bv[j]; Cv[q*4+j] = cv[j]; }
        }
        float y = 0.f;
        #pragma unroll
        for (int n = 0; n < NSTATE; ++n) {
            float a = expf(dl * A[n]);
            s[n] = fmaf(a, s[n], dlh * Bv[n]);
            y = fmaf(s[n], Cv[n], y);
        }
        y = fmaf(hv, Dd, y);
        float sig = 1.f / (1.f + expf(-rv));
        y *= rv * sig;
        yb[row * DINNER + d] = f2bf(y);
    }
}

extern "C" void kernel_launch(void* const* d_in, const int* in_sizes, int n_in,
                              void* d_out, int out_size, void* d_ws, size_t ws_size,
                              hipStream_t stream)
{
    const float* x     = (const float*)d_in[0];
    const float* Win   = (const float*)d_in[1];
    const float* convw = (const float*)d_in[2];
    const float* convb = (const float*)d_in[3];
    const float* Wxp   = (const float*)d_in[4];
    const float* Wdt   = (const float*)d_in[5];   // 64 x 2048 f32
    const float* dtb   = (const float*)d_in[6];
    const float* Alog  = (const float*)d_in[7];
    const float* Dp    = (const float*)d_in[8];
    const float* Wout  = (const float*)d_in[9];
    float* out = (float*)d_out;

    char* base = (char*)d_ws; size_t off = 0;
    auto alloc = [&](size_t bytes) -> char* {
        char* q = base + off;
        off = (off + bytes + 255) & ~(size_t)255;
        return q;
    };
    ushort_t* WtIn  = (ushort_t*)alloc((size_t)4096 * 1024 * 2);
    ushort_t* WtOut = (ushort_t*)alloc((size_t)1024 * 2048 * 2);
    ushort_t* WtXp  = (ushort_t*)alloc((size_t)96   * 2048 * 2);
    ushort_t* xb    = (ushort_t*)alloc((size_t)BL * DIM * 2);
    ushort_t* xrb   = (ushort_t*)alloc((size_t)BL * 4096 * 2);   // bf16 xp|res
    ushort_t* hb    = (ushort_t*)alloc((size_t)BL * DINNER * 2);
    float*    xdbl  = (float*)   alloc((size_t)BL * XDBLW * 4);
    ushort_t* dltbf = (ushort_t*)alloc((size_t)BL * DINNER * 2);
    ushort_t* yb    = (ushort_t*)alloc((size_t)BL * DINNER * 2);
    float*    Pbuf  = (float*)   alloc((size_t)BATCH * NCHUNK * DINNER * NSTATE * 4);  // 8 MB
    float*    Sbuf  = (float*)   alloc((size_t)BATCH * NCHUNK * DINNER * NSTATE * 4);  // 8 MB
    float*    Ppart = (float*)   alloc((size_t)KSLICE * BL * XDBLW * 4);               // 12.6 MB
    (void)ws_size;

    // fused prep: 3 transposes + x->bf16
    prep_fused<<<dim3(8384), 256, 0, stream>>>(Win, WtIn, Wout, WtOut, Wxp, WtXp, x, xb);

    // G1: xr = x @ in_proj_w   (2048 x 4096, K=1024) -> bf16
    gemm_lds<<<dim3(4096/128, BL/128), 256, 0, stream>>>(
        xb, DIM, WtIn, DIM, DIM, nullptr, xrb, 2*DINNER);

    conv_silu<<<dim3(DINNER/256, BL), 256, 0, stream>>>(xrb, convw, convb, hb);

    // G2: xdbl partials (split-K) + reduce
    gemm_n96_splitk<<<dim3(KSLICE, BL/128), 256, 0, stream>>>(hb, WtXp, Ppart);
    g2_reduce<<<dim3(BL * 24 / 256), 256, 0, stream>>>(Ppart, xdbl);

    // delta = softplus(dlt @ dt_proj_w + dt_b) -> bf16 (tiled, W staged once/block)
    delta_v5<<<dim3(8 * (BL / 32)), 256, 0, stream>>>(xdbl, Wdt, dtb, dltbf);

    // chunked parallel scan (NCHUNK=32)
    scan_p1<<<dim3(8 * BATCH * NCHUNK), 256, 0, stream>>>(dltbf, hb, xdbl, Alog, Pbuf, Sbuf);
    scan_p2<<<dim3(BATCH * DINNER * NSTATE / 256), 256, 0, stream>>>(Pbuf, Sbuf);
    scan_p3<<<dim3(8 * BATCH * NCHUNK), 256, 0, stream>>>(dltbf, hb, xdbl, xrb, Alog, Dp, Sbuf, yb);

    // G4: out = y @ out_proj_w (2048 x 1024, K=2048) -> f32 d_out
    gemm_lds<<<dim3(DIM/128, BL/128), 256, 0, stream>>>(
        yb, DINNER, WtOut, DINNER, DINNER, out, nullptr, DIM);
}